// Round 2
// baseline (844.946 us; speedup 1.0000x reference)
//
#include <hip/hip_runtime.h>
#include <stdint.h>

// EncoderLayer on MI355X (gfx950), bf16 MFMA pipeline.
// B=4, S=2048, HID=1024, HEADS=16, HD=64, PF=4096. M = B*S = 8192.

typedef __bf16 bf16;
typedef __bf16 bf16x4 __attribute__((ext_vector_type(4)));
typedef __bf16 bf16x8 __attribute__((ext_vector_type(8)));
typedef short  s16x4  __attribute__((ext_vector_type(4)));
typedef float  f32x4  __attribute__((ext_vector_type(4)));

__device__ __forceinline__ bf16 f2b(float x){
  uint32_t u = __builtin_bit_cast(uint32_t, x);
  uint32_t r = (u + 0x7FFFu + ((u >> 16) & 1u)) >> 16;   // RNE
  return __builtin_bit_cast(bf16, (uint16_t)r);
}

__device__ __forceinline__ float ex2(float x){
#if __has_builtin(__builtin_amdgcn_exp2f)
  return __builtin_amdgcn_exp2f(x);
#else
  return __exp2f(x);
#endif
}

// 16x16x16 bf16 MFMA (A,B: 4 bf16 / 2 VGPRs each; D: 4 f32)
__device__ __forceinline__ f32x4 mfma16bf(bf16x4 a, bf16x4 b, f32x4 c){
#if __has_builtin(__builtin_amdgcn_mfma_f32_16x16x16_bf16)
  return __builtin_amdgcn_mfma_f32_16x16x16_bf16(a, b, c, 0, 0, 0);
#elif __has_builtin(__builtin_amdgcn_mfma_f32_16x16x16bf16_1k)
  return __builtin_amdgcn_mfma_f32_16x16x16bf16_1k(
      __builtin_bit_cast(s16x4, a), __builtin_bit_cast(s16x4, b), c, 0, 0, 0);
#else
  f32x4 d = c;
  asm volatile("v_mfma_f32_16x16x16_bf16 %0, %1, %2, %0"
               : "+v"(d)
               : "v"(__builtin_bit_cast(s16x4, a)), "v"(__builtin_bit_cast(s16x4, b)));
  return d;
#endif
}

// async global->LDS, 16B per lane (dest = wave-uniform base + lane*16)
__device__ __forceinline__ void gload_lds16(const bf16* g, bf16* l){
  __builtin_amdgcn_global_load_lds(
      (const __attribute__((address_space(1))) void*)g,
      (__attribute__((address_space(3))) void*)l, 16, 0, 0);
}

// ---------------- cast f32 -> bf16 (vectorized) ----------------
__global__ __launch_bounds__(256) void castb_kernel(const float* __restrict__ in,
                                                    bf16* __restrict__ out, int n4){
  const int i = blockIdx.x*256 + threadIdx.x;
  if (i >= n4) return;
  const float4 v = ((const float4*)in)[i];
  bf16x4 u = { f2b(v.x), f2b(v.y), f2b(v.z), f2b(v.w) };
  *(bf16x4*)(out + (size_t)i*4) = u;
}

// ---------------- transpose+cast W[K][N] f32 -> Wt[N][K] bf16 ----------------
__global__ void transcast_kernel(const float* __restrict__ W, bf16* __restrict__ Wt,
                                 int K, int N){
  __shared__ float t[32][33];
  const int x = threadIdx.x, y = threadIdx.y;           // (32,8)
  const int n0 = blockIdx.x*32, k0 = blockIdx.y*32;
  #pragma unroll
  for (int r=0;r<4;r++) t[y+8*r][x] = W[(size_t)(k0+y+8*r)*N + n0+x];
  __syncthreads();
  #pragma unroll
  for (int r=0;r<4;r++) Wt[(size_t)(n0+y+8*r)*K + k0+x] = f2b(t[x][y+8*r]);
}

// ---------------- GEMM: C = A[M][K] * Bt[N][K]^T + bias ----------------
// 128x128 tile, 4 waves (2x2), wave = 64x64 = 4x4 frags of 16x16x32 MFMA.
// LDS [128][32] bf16, 16B-slot XOR swizzle slot^=(row>>1)&3; staging via
// global_load_lds w16 with the swizzle applied to the GLOBAL source address
// (LDS stays linear; involution => read side unchanged).
// OMODE: 0=f32, 1=bf16, 2=bf16+swish, 3=bf16 V-transposed [b*1024+col][2048]
template<int OMODE>
__global__ __launch_bounds__(256) void gemm_bt_kernel(
    const bf16* __restrict__ A, const bf16* __restrict__ Bt,
    const float* __restrict__ bias, void* __restrict__ C,
    int M, int N, int K)
{
  __shared__ bf16 As[128*32];
  __shared__ bf16 Bs[128*32];
  const int tid = threadIdx.x;
  const int w = tid >> 6, lane = tid & 63;
  const int wr = w >> 1, wc = w & 1;
  const int g16 = lane >> 4, l16 = lane & 15;
  const int m0 = blockIdx.y*128, n0 = blockIdx.x*128;

  // chunk c = tid (and c+256): LDS linear offset c*16B = row(c>>2)*64B + (c&3)*16B.
  // data placed there must be global slot (c&3) ^ ((c>>3)&3)  [= (c&3) ^ ((row>>1)&3)]
  const int c = tid;
  const int row1  = c >> 2;
  const int slot1 = (c & 3) ^ ((c >> 3) & 3);            // same for c+256
  const bf16* gA1 = A  + (size_t)(m0 + row1)*K + slot1*8;
  const bf16* gA2 = gA1 + (size_t)64*K;                  // row+64, same slot
  const bf16* gB1 = Bt + (size_t)(n0 + row1)*K + slot1*8;
  const bf16* gB2 = gB1 + (size_t)64*K;
  bf16* lA1 = &As[(size_t)w*512];                        // wave-uniform bases
  bf16* lA2 = &As[(size_t)w*512 + 2048];
  bf16* lB1 = &Bs[(size_t)w*512];
  bf16* lB2 = &Bs[(size_t)w*512 + 2048];

  f32x4 acc[4][4];
  const f32x4 fz = {0.f,0.f,0.f,0.f};
  #pragma unroll
  for (int m=0;m<4;m++)
    #pragma unroll
    for (int n=0;n<4;n++) acc[m][n] = fz;

  for (int k0=0; k0<K; k0+=32){
    __syncthreads();                       // prev-iter LDS reads done
    gload_lds16(gA1 + k0, lA1);
    gload_lds16(gA2 + k0, lA2);
    gload_lds16(gB1 + k0, lB1);
    gload_lds16(gB2 + k0, lB2);
    __syncthreads();                       // compiler drains vmcnt(0) before barrier
    bf16x8 af[4], bfv[4];
    #pragma unroll
    for (int m=0;m<4;m++){
      const int r = wr*64 + m*16 + l16;
      af[m] = *(const bf16x8*)&As[r*32 + ((g16 ^ ((r>>1)&3))<<3)];
    }
    #pragma unroll
    for (int n=0;n<4;n++){
      const int r = wc*64 + n*16 + l16;
      bfv[n] = *(const bf16x8*)&Bs[r*32 + ((g16 ^ ((r>>1)&3))<<3)];
    }
    #pragma unroll
    for (int m=0;m<4;m++)
      #pragma unroll
      for (int n=0;n<4;n++)
        acc[m][n] = __builtin_amdgcn_mfma_f32_16x16x32_bf16(af[m], bfv[n], acc[m][n], 0, 0, 0);
  }

  // epilogue: D[i][j]: j = lane&15, i = 4*(lane>>4)+reg  [measured layout]
  const int cb = n0 + wc*64 + l16;
  #pragma unroll
  for (int n=0;n<4;n++){
    const int col = cb + n*16;
    const float bv = bias[col];
    #pragma unroll
    for (int m=0;m<4;m++){
      const int rbase = m0 + wr*64 + m*16 + g16*4;
      #pragma unroll
      for (int r=0;r<4;r++){
        float v = acc[m][n][r] + bv;
        const size_t row = (size_t)(rbase + r);
        if constexpr (OMODE==0){
          ((float*)C)[row*N + col] = v;
        } else if constexpr (OMODE==1){
          ((bf16*)C)[row*N + col] = f2b(v);
        } else if constexpr (OMODE==2){
          v = v / (1.f + __expf(-v));               // swish
          ((bf16*)C)[row*N + col] = f2b(v);
        } else {                                    // V transposed: [b*1024+col][2048]
          const size_t bq = row >> 11, s = row & 2047;
          ((bf16*)C)[(bq*1024 + (size_t)col)*2048 + s] = f2b(v);
        }
      }
    }
  }
}

// ---------------- flash attention (swapped QK^T, in-register softmax) ------
// grid (S/128, HEADS, B), 4 waves/block; wave owns 32 q-rows (2 groups of 16).
// KV tile = 64 (4 subtiles of 16).
// S^T = mfma_16x16x32(A=K, B=Q): D col=l16=q, row=4*g16+r=kv  -> softmax over
// kv is 15 in-reg ops + 2 shfl. P sits at (g16,r) == B-operand k-map of
// mfma_16x16x16 (k=4*g16+e), so PV needs NO cross-lane exchange and NO LDS.
// O^T = mfma_16x16x16(A=V^T, B=P^T): D col=q, row=d_local=4*g16+r.
__global__ __launch_bounds__(256) void attn_kernel(
    const bf16* __restrict__ Q, const bf16* __restrict__ Km,
    const bf16* __restrict__ Vt, const int* __restrict__ msk,
    bf16* __restrict__ O)
{
  const int tid = threadIdx.x;
  const int w = tid>>6, lane = tid&63;
  const int g16 = lane>>4, l16 = lane&15;
  const int b = blockIdx.z, h = blockIdx.y;
  const int q0 = blockIdx.x*128 + w*32;

  const bf16* Kb = Km + (size_t)b*2048*1024 + h*64;
  const bf16* Vb = Vt + (size_t)(b*16 + h)*64*2048;
  const int*  mb = msk + b*2048;

  // Q fragments (B-operand): col=q=l16, k=d=g16*8+e (+32)
  bf16x8 qf[2][2];
  #pragma unroll
  for (int qg=0;qg<2;qg++){
    const bf16* qp = Q + (size_t)(b*2048 + q0 + qg*16 + l16)*1024 + h*64 + g16*8;
    qf[qg][0] = *(const bf16x8*)qp;
    qf[qg][1] = *(const bf16x8*)(qp + 32);
  }

  float m_[2] = {-3e38f, -3e38f};
  float l_[2] = {0.f, 0.f};
  const f32x4 fz = {0.f,0.f,0.f,0.f};
  f32x4 xa[2][4];
  #pragma unroll
  for (int qg=0;qg<2;qg++)
    #pragma unroll
    for (int jd=0;jd<4;jd++) xa[qg][jd] = fz;

  const float SC = 0.18033688011112042f;   // log2(e)/sqrt(64)

  for (int kv0=0; kv0<2048; kv0+=64){
    // ---- QK^T: 4 subtiles of 16 kv ----
    f32x4 st[2][4];
    #pragma unroll
    for (int t=0;t<4;t++){
      const bf16* kp = Kb + (size_t)(kv0 + t*16 + l16)*1024 + g16*8;
      const bf16x8 k0v = *(const bf16x8*)kp;
      const bf16x8 k1v = *(const bf16x8*)(kp + 32);
      #pragma unroll
      for (int qg=0;qg<2;qg++){
        f32x4 a = fz;
        a = __builtin_amdgcn_mfma_f32_16x16x32_bf16(k0v, qf[qg][0], a, 0,0,0);
        a = __builtin_amdgcn_mfma_f32_16x16x32_bf16(k1v, qf[qg][1], a, 0,0,0);
        st[qg][t] = a;
      }
    }
    // ---- mask (per-lane kv = kv0 + t*16 + 4*g16 + r) ----
    int mar[16];
    #pragma unroll
    for (int t=0;t<4;t++){
      const int4 m4 = *(const int4*)(mb + kv0 + t*16 + 4*g16);
      mar[t*4+0]=m4.x; mar[t*4+1]=m4.y; mar[t*4+2]=m4.z; mar[t*4+3]=m4.w;
    }
    // ---- softmax + pack P (per q-group) ----
    bf16x4 pq[2][4];
    #pragma unroll
    for (int qg=0;qg<2;qg++){
      float v[16];
      #pragma unroll
      for (int t=0;t<4;t++)
        #pragma unroll
        for (int r=0;r<4;r++)
          v[t*4+r] = (mar[t*4+r]==0) ? -1.5e10f : st[qg][t][r]*SC;
      float tm = v[0];
      #pragma unroll
      for (int i=1;i<16;i++) tm = fmaxf(tm, v[i]);
      tm = fmaxf(tm, __shfl_xor(tm, 16, 64));
      tm = fmaxf(tm, __shfl_xor(tm, 32, 64));
      if (!__all(tm <= m_[qg] + 8.f)){       // defer-max (T13)
        const float mn = fmaxf(m_[qg], tm);
        const float sc = ex2(m_[qg] - mn);
        l_[qg] *= sc;
        #pragma unroll
        for (int jd=0;jd<4;jd++) xa[qg][jd] *= sc;
        m_[qg] = mn;
      }
      float rs = 0.f;
      #pragma unroll
      for (int t=0;t<4;t++){
        #pragma unroll
        for (int r=0;r<4;r++){
          const float pv = ex2(v[t*4+r] - m_[qg]);
          rs += pv;
          pq[qg][t][r] = (bf16)pv;
        }
      }
      rs += __shfl_xor(rs, 16, 64);
      rs += __shfl_xor(rs, 32, 64);
      l_[qg] += rs;
    }
    // ---- PV: O^T += V^T * P^T, 16x16x16, A=V^T (k=4*g16+e) ----
    #pragma unroll
    for (int t=0;t<4;t++){
      #pragma unroll
      for (int jd=0;jd<4;jd++){
        const bf16x4 vv = *(const bf16x4*)(Vb + (size_t)(jd*16 + l16)*2048 + kv0 + t*16 + 4*g16);
        xa[0][jd] = mfma16bf(vv, pq[0][t], xa[0][jd]);
        xa[1][jd] = mfma16bf(vv, pq[1][t], xa[1][jd]);
      }
    }
  }

  // ---- write O: lane holds q=l16 (per group), d = jd*16 + 4*g16 + r ----
  #pragma unroll
  for (int qg=0;qg<2;qg++){
    const float rl = 1.f / l_[qg];
    const size_t row = (size_t)(b*2048 + q0 + qg*16 + l16);
    #pragma unroll
    for (int jd=0;jd<4;jd++){
      bf16x4 ov = { f2b(xa[qg][jd][0]*rl), f2b(xa[qg][jd][1]*rl),
                    f2b(xa[qg][jd][2]*rl), f2b(xa[qg][jd][3]*rl) };
      *(bf16x4*)(O + row*1024 + h*64 + jd*16 + 4*g16) = ov;
    }
  }
}

// ---------------- residual + layernorm (row = 1024) ----------------
__global__ __launch_bounds__(256) void addln_kernel(
    const float* __restrict__ X, const float* __restrict__ R,
    const float* __restrict__ g, const float* __restrict__ be,
    float* __restrict__ of, bf16* __restrict__ ob)
{
  const int row = blockIdx.x, tid = threadIdx.x;
  const float4 vx = ((const float4*)(X + (size_t)row*1024))[tid];
  const float4 vr = ((const float4*)(R + (size_t)row*1024))[tid];
  const float a0 = vx.x+vr.x, a1 = vx.y+vr.y, a2 = vx.z+vr.z, a3 = vx.w+vr.w;
  float s = a0+a1+a2+a3;
  float q = a0*a0 + a1*a1 + a2*a2 + a3*a3;
  #pragma unroll
  for (int off=1; off<64; off<<=1){
    s += __shfl_xor(s, off, 64);
    q += __shfl_xor(q, off, 64);
  }
  __shared__ float sb[8];
  if ((tid&63)==0){ sb[tid>>6] = s; sb[4+(tid>>6)] = q; }
  __syncthreads();
  s = sb[0]+sb[1]+sb[2]+sb[3];
  q = sb[4]+sb[5]+sb[6]+sb[7];
  const float mu = s*(1.f/1024.f);
  const float rs = rsqrtf(q*(1.f/1024.f) - mu*mu + 1e-5f);
  const float4 gg = ((const float4*)g)[tid];
  const float4 bb = ((const float4*)be)[tid];
  const float o0 = (a0-mu)*rs*gg.x + bb.x;
  const float o1 = (a1-mu)*rs*gg.y + bb.y;
  const float o2 = (a2-mu)*rs*gg.z + bb.z;
  const float o3 = (a3-mu)*rs*gg.w + bb.w;
  float4 o; o.x=o0; o.y=o1; o.z=o2; o.w=o3;
  ((float4*)(of + (size_t)row*1024))[tid] = o;
  if (ob){
    bf16x4 u = { f2b(o0), f2b(o1), f2b(o2), f2b(o3) };
    *(bf16x4*)(ob + (size_t)row*1024 + tid*4) = u;
  }
}

// ---------------- launch ----------------
extern "C" void kernel_launch(void* const* d_in, const int* in_sizes, int n_in,
                              void* d_out, int out_size, void* d_ws, size_t ws_size,
                              hipStream_t stream)
{
  const float* src  = (const float*)d_in[0];
  const int*   mask = (const int*)  d_in[1];
  const float* Wq = (const float*)d_in[2];  const float* bq = (const float*)d_in[3];
  const float* Wk = (const float*)d_in[4];  const float* bk = (const float*)d_in[5];
  const float* Wv = (const float*)d_in[6];  const float* bv = (const float*)d_in[7];
  const float* Wo = (const float*)d_in[8];  const float* bo = (const float*)d_in[9];
  const float* W1 = (const float*)d_in[10]; const float* b1 = (const float*)d_in[11];
  const float* W2 = (const float*)d_in[12]; const float* b2 = (const float*)d_in[13];
  const float* g1 = (const float*)d_in[14]; const float* be1 = (const float*)d_in[15];
  const float* g2 = (const float*)d_in[16]; const float* be2 = (const float*)d_in[17];

  char* ws = (char*)d_ws;
  const size_t MB = 1u<<20;
  bf16* srcb = (bf16*)(ws + 0*MB);     // 16 MB  [dead after QKV gemms]
  bf16* Wqt  = (bf16*)(ws + 16*MB);    // 2 MB
  bf16* Wkt  = (bf16*)(ws + 18*MB);
  bf16* Wvt  = (bf16*)(ws + 20*MB);
  bf16* Wot  = (bf16*)(ws + 22*MB);
  bf16* W1t  = (bf16*)(ws + 24*MB);    // 8 MB
  bf16* W2t  = (bf16*)(ws + 32*MB);    // 8 MB
  bf16* Qb   = (bf16*)(ws + 40*MB);    // 16 MB [dead after attn]
  bf16* Kb   = (bf16*)(ws + 56*MB);    // 16 MB [dead after attn]
  bf16* Vtb  = (bf16*)(ws + 72*MB);    // 16 MB [dead after attn]
  bf16* AO   = (bf16*)(ws + 88*MB);    // 16 MB [dead after O-proj]
  float* X1  = (float*)(ws + 40*MB);   // 32 MB over Qb+Kb
  float* S1F = (float*)(ws + 72*MB);   // 32 MB over Vtb+AO
  bf16*  S1B = (bf16*)(ws + 0*MB);     // 16 MB over srcb
  bf16*  H1  = (bf16*)(ws + 104*MB);   // 64 MB
  float* F2  = (float*)(ws + 40*MB);   // 32 MB over X1 (dead after LN1)

  // casts + weight transposes
  castb_kernel<<<8192, 256, 0, stream>>>(src, srcb, 8192*1024/4);
  transcast_kernel<<<dim3(32,32),  dim3(32,8), 0, stream>>>(Wq, Wqt, 1024, 1024);
  transcast_kernel<<<dim3(32,32),  dim3(32,8), 0, stream>>>(Wk, Wkt, 1024, 1024);
  transcast_kernel<<<dim3(32,32),  dim3(32,8), 0, stream>>>(Wv, Wvt, 1024, 1024);
  transcast_kernel<<<dim3(32,32),  dim3(32,8), 0, stream>>>(Wo, Wot, 1024, 1024);
  transcast_kernel<<<dim3(128,32), dim3(32,8), 0, stream>>>(W1, W1t, 1024, 4096);
  transcast_kernel<<<dim3(32,128), dim3(32,8), 0, stream>>>(W2, W2t, 4096, 1024);

  // QKV projections
  gemm_bt_kernel<1><<<dim3(8,64),  256, 0, stream>>>(srcb, Wqt, bq, Qb,  8192, 1024, 1024);
  gemm_bt_kernel<1><<<dim3(8,64),  256, 0, stream>>>(srcb, Wkt, bk, Kb,  8192, 1024, 1024);
  gemm_bt_kernel<3><<<dim3(8,64),  256, 0, stream>>>(srcb, Wvt, bv, Vtb, 8192, 1024, 1024);

  // attention
  attn_kernel<<<dim3(16,16,4), 256, 0, stream>>>(Qb, Kb, Vtb, mask, AO);

  // output projection + LN1
  gemm_bt_kernel<0><<<dim3(8,64),  256, 0, stream>>>(AO, Wot, bo, X1, 8192, 1024, 1024);
  addln_kernel<<<8192, 256, 0, stream>>>(X1, src, g1, be1, S1F, S1B);

  // FFN (swish) + LN2 -> d_out
  gemm_bt_kernel<2><<<dim3(32,64), 256, 0, stream>>>(S1B, W1t, b1, H1, 8192, 4096, 1024);
  gemm_bt_kernel<0><<<dim3(8,64),  256, 0, stream>>>(H1,  W2t, b2, F2, 8192, 1024, 4096);
  addln_kernel<<<8192, 256, 0, stream>>>(F2, S1F, g2, be2, (float*)d_out, (bf16*)nullptr);
}

// Round 3
// 727.589 us; speedup vs baseline: 1.1613x; 1.1613x over previous
//
#include <hip/hip_runtime.h>
#include <stdint.h>

// EncoderLayer on MI355X (gfx950), bf16 MFMA pipeline.
// B=4, S=2048, HID=1024, HEADS=16, HD=64, PF=4096. M = B*S = 8192.

typedef __bf16 bf16;
typedef __bf16 bf16x4 __attribute__((ext_vector_type(4)));
typedef __bf16 bf16x8 __attribute__((ext_vector_type(8)));
typedef short  s16x4  __attribute__((ext_vector_type(4)));
typedef float  f32x4  __attribute__((ext_vector_type(4)));

__device__ __forceinline__ bf16 f2b(float x){
  uint32_t u = __builtin_bit_cast(uint32_t, x);
  uint32_t r = (u + 0x7FFFu + ((u >> 16) & 1u)) >> 16;   // RNE
  return __builtin_bit_cast(bf16, (uint16_t)r);
}

__device__ __forceinline__ float ex2(float x){
#if __has_builtin(__builtin_amdgcn_exp2f)
  return __builtin_amdgcn_exp2f(x);
#else
  return __exp2f(x);
#endif
}

// 16x16x16 bf16 MFMA (A,B: 4 bf16 / 2 VGPRs each; D: 4 f32)
__device__ __forceinline__ f32x4 mfma16bf(bf16x4 a, bf16x4 b, f32x4 c){
#if __has_builtin(__builtin_amdgcn_mfma_f32_16x16x16_bf16)
  return __builtin_amdgcn_mfma_f32_16x16x16_bf16(a, b, c, 0, 0, 0);
#elif __has_builtin(__builtin_amdgcn_mfma_f32_16x16x16bf16_1k)
  return __builtin_amdgcn_mfma_f32_16x16x16bf16_1k(
      __builtin_bit_cast(s16x4, a), __builtin_bit_cast(s16x4, b), c, 0, 0, 0);
#else
  f32x4 d = c;
  asm volatile("v_mfma_f32_16x16x16_bf16 %0, %1, %2, %0"
               : "+v"(d)
               : "v"(__builtin_bit_cast(s16x4, a)), "v"(__builtin_bit_cast(s16x4, b)));
  return d;
#endif
}

// ---------------- cast f32 -> bf16 (vectorized) ----------------
__global__ __launch_bounds__(256) void castb_kernel(const float* __restrict__ in,
                                                    bf16* __restrict__ out, int n4){
  const int i = blockIdx.x*256 + threadIdx.x;
  if (i >= n4) return;
  const float4 v = ((const float4*)in)[i];
  bf16x4 u = { f2b(v.x), f2b(v.y), f2b(v.z), f2b(v.w) };
  *(bf16x4*)(out + (size_t)i*4) = u;
}

// ---------------- transpose+cast W[K][N] f32 -> Wt[N][K] bf16 ----------------
__global__ void transcast_kernel(const float* __restrict__ W, bf16* __restrict__ Wt,
                                 int K, int N){
  __shared__ float t[32][33];
  const int x = threadIdx.x, y = threadIdx.y;           // (32,8)
  const int n0 = blockIdx.x*32, k0 = blockIdx.y*32;
  #pragma unroll
  for (int r=0;r<4;r++) t[y+8*r][x] = W[(size_t)(k0+y+8*r)*N + n0+x];
  __syncthreads();
  #pragma unroll
  for (int r=0;r<4;r++) Wt[(size_t)(n0+y+8*r)*K + k0+x] = f2b(t[x][y+8*r]);
}

// ---------------- GEMM: C = A[M][K] * Bt[N][K]^T + bias ----------------
// 128x128 tile, 4 waves (2x2), wave = 64x64 = 4x4 frags of 16x16x32 MFMA.
// Reg-staged LDS with next-K-tile register prefetch (known-good 834 TF).
// LDS [128][32] bf16, 16B-slot XOR swizzle slot^=(row>>1)&3.
// OMODE: 0=f32, 1=bf16 (scaled by oscale), 2=bf16+swish,
//        3=bf16 V-transposed [b*1024+col][2048]
template<int OMODE>
__global__ __launch_bounds__(256) void gemm_bt_kernel(
    const bf16* __restrict__ A, const bf16* __restrict__ Bt,
    const float* __restrict__ bias, void* __restrict__ C,
    int M, int N, int K, float oscale)
{
  __shared__ bf16 As[128*32];
  __shared__ bf16 Bs[128*32];
  const int tid = threadIdx.x;
  const int w = tid >> 6, lane = tid & 63;
  const int wr = w >> 1, wc = w & 1;
  const int g16 = lane >> 4, l16 = lane & 15;
  const int m0 = blockIdx.y*128, n0 = blockIdx.x*128;

  const int ar = tid >> 2, asl = tid & 3;
  const bf16* gA = A  + (size_t)(m0+ar)*K + asl*8;
  const bf16* gB = Bt + (size_t)(n0+ar)*K + asl*8;
  const int sw0 = (ar>>1)&3;
  const int la = ar*32      + ((asl ^ sw0)<<3);
  const int lb = (ar+64)*32 + ((asl ^ sw0)<<3);

  f32x4 acc[4][4];
  const f32x4 fz = {0.f,0.f,0.f,0.f};
  #pragma unroll
  for (int m=0;m<4;m++)
    #pragma unroll
    for (int n=0;n<4;n++) acc[m][n] = fz;

  bf16x8 ra0 = *(const bf16x8*)gA;
  bf16x8 ra1 = *(const bf16x8*)(gA + (size_t)64*K);
  bf16x8 rb0 = *(const bf16x8*)gB;
  bf16x8 rb1 = *(const bf16x8*)(gB + (size_t)64*K);

  for (int k0=0; k0<K; k0+=32){
    __syncthreads();
    *(bf16x8*)&As[la] = ra0;
    *(bf16x8*)&As[lb] = ra1;
    *(bf16x8*)&Bs[la] = rb0;
    *(bf16x8*)&Bs[lb] = rb1;
    __syncthreads();
    if (k0 + 32 < K){
      ra0 = *(const bf16x8*)(gA + k0+32);
      ra1 = *(const bf16x8*)(gA + (size_t)64*K + k0+32);
      rb0 = *(const bf16x8*)(gB + k0+32);
      rb1 = *(const bf16x8*)(gB + (size_t)64*K + k0+32);
    }
    bf16x8 af[4], bfv[4];
    #pragma unroll
    for (int m=0;m<4;m++){
      const int r = wr*64 + m*16 + l16;
      af[m] = *(const bf16x8*)&As[r*32 + ((g16 ^ ((r>>1)&3))<<3)];
    }
    #pragma unroll
    for (int n=0;n<4;n++){
      const int r = wc*64 + n*16 + l16;
      bfv[n] = *(const bf16x8*)&Bs[r*32 + ((g16 ^ ((r>>1)&3))<<3)];
    }
    #pragma unroll
    for (int m=0;m<4;m++)
      #pragma unroll
      for (int n=0;n<4;n++)
        acc[m][n] = __builtin_amdgcn_mfma_f32_16x16x32_bf16(af[m], bfv[n], acc[m][n], 0, 0, 0);
  }

  // epilogue: D[i][j]: j = lane&15, i = 4*(lane>>4)+reg  [measured layout]
  const int cb = n0 + wc*64 + l16;
  #pragma unroll
  for (int n=0;n<4;n++){
    const int col = cb + n*16;
    const float bv = bias[col];
    #pragma unroll
    for (int m=0;m<4;m++){
      const int rbase = m0 + wr*64 + m*16 + g16*4;
      #pragma unroll
      for (int r=0;r<4;r++){
        float v = acc[m][n][r] + bv;
        const size_t row = (size_t)(rbase + r);
        if constexpr (OMODE==0){
          ((float*)C)[row*N + col] = v;
        } else if constexpr (OMODE==1){
          ((bf16*)C)[row*N + col] = f2b(v * oscale);
        } else if constexpr (OMODE==2){
          v = v / (1.f + __expf(-v));               // swish
          ((bf16*)C)[row*N + col] = f2b(v);
        } else {                                    // V transposed: [b*1024+col][2048]
          const size_t bq = row >> 11, s = row & 2047;
          ((bf16*)C)[(bq*1024 + (size_t)col)*2048 + s] = f2b(v);
        }
      }
    }
  }
}

// ---------------- flash attention (swapped QK^T, reg-dbuf K prefetch) ------
// grid 1024 linear blocks, XCD-aware: all 16 q-tiles of one (b,h) on one XCD.
// 4 waves/block; wave owns 32 q-rows (2 groups of 16). KV tile = 64.
// Q is pre-scaled by 0.125*log2e in its GEMM epilogue -> softmax in exp2 domain.
// S^T = mfma_16x16x32(A=K, B=Q): D col=l16=q, row=4*g16+r=kv. P sits exactly
// at the B-operand k-map of mfma_16x16x16 -> PV needs no exchange, no LDS.
__global__ __launch_bounds__(256) void attn_kernel(
    const bf16* __restrict__ Q, const bf16* __restrict__ Km,
    const bf16* __restrict__ Vt, const int* __restrict__ msk,
    bf16* __restrict__ O)
{
  const int tid = threadIdx.x;
  const int w = tid>>6, lane = tid&63;
  const int g16 = lane>>4, l16 = lane&15;
  const int lin = blockIdx.x;                 // 0..1023
  const int xcd = lin & 7, idx = lin >> 3;    // assume XCD = blockIdx % 8
  const int bh  = xcd*8 + (idx >> 4);         // 8 (b,h) groups per XCD
  const int qt  = idx & 15;
  const int b = bh >> 4, h = bh & 15;
  const int q0 = qt*128 + w*32;

  const bf16* Kb = Km + (size_t)b*2048*1024 + h*64;
  const bf16* Vb = Vt + (size_t)(b*16 + h)*64*2048;
  const int*  mb = msk + b*2048;

  // Q fragments (B-operand): col=q=l16, k=d=g16*8+e (+32)
  bf16x8 qf[2][2];
  #pragma unroll
  for (int qg=0;qg<2;qg++){
    const bf16* qp = Q + (size_t)(b*2048 + q0 + qg*16 + l16)*1024 + h*64 + g16*8;
    qf[qg][0] = *(const bf16x8*)qp;
    qf[qg][1] = *(const bf16x8*)(qp + 32);
  }

  float m_[2] = {-3e38f, -3e38f};
  float l_[2] = {0.f, 0.f};
  const f32x4 fz = {0.f,0.f,0.f,0.f};
  f32x4 xa[2][4];
  #pragma unroll
  for (int qg=0;qg<2;qg++)
    #pragma unroll
    for (int jd=0;jd<4;jd++) xa[qg][jd] = fz;

  bf16x8 kA[4][2], kB[4][2];

  auto loadK = [&](int kv0, bf16x8 (&kk)[4][2]){
    #pragma unroll
    for (int t=0;t<4;t++){
      const bf16* kp = Kb + (size_t)(kv0 + t*16 + l16)*1024 + g16*8;
      kk[t][0] = *(const bf16x8*)kp;
      kk[t][1] = *(const bf16x8*)(kp + 32);
    }
  };

  auto compute = [&](int kv0, bf16x8 (&kk)[4][2]){
    // V + mask loads issued first; consumed only after softmax -> overlap
    bf16x4 vv[4][4];
    int4 mm[4];
    #pragma unroll
    for (int t=0;t<4;t++){
      mm[t] = *(const int4*)(mb + kv0 + t*16 + 4*g16);
      #pragma unroll
      for (int jd=0;jd<4;jd++)
        vv[t][jd] = *(const bf16x4*)(Vb + (size_t)(jd*16 + l16)*2048 + kv0 + t*16 + 4*g16);
    }
    f32x4 st[2][4];
    __builtin_amdgcn_s_setprio(1);
    #pragma unroll
    for (int t=0;t<4;t++){
      #pragma unroll
      for (int qg=0;qg<2;qg++){
        f32x4 a = fz;
        a = __builtin_amdgcn_mfma_f32_16x16x32_bf16(kk[t][0], qf[qg][0], a, 0,0,0);
        a = __builtin_amdgcn_mfma_f32_16x16x32_bf16(kk[t][1], qf[qg][1], a, 0,0,0);
        st[qg][t] = a;
      }
    }
    __builtin_amdgcn_s_setprio(0);
    bf16x4 pq[2][4];
    #pragma unroll
    for (int qg=0;qg<2;qg++){
      float v[16];
      #pragma unroll
      for (int t=0;t<4;t++){
        v[t*4+0] = (mm[t].x==0) ? -1.5e10f : st[qg][t][0];
        v[t*4+1] = (mm[t].y==0) ? -1.5e10f : st[qg][t][1];
        v[t*4+2] = (mm[t].z==0) ? -1.5e10f : st[qg][t][2];
        v[t*4+3] = (mm[t].w==0) ? -1.5e10f : st[qg][t][3];
      }
      float tm = v[0];
      #pragma unroll
      for (int i=1;i<16;i++) tm = fmaxf(tm, v[i]);
      tm = fmaxf(tm, __shfl_xor(tm, 16, 64));
      tm = fmaxf(tm, __shfl_xor(tm, 32, 64));
      if (!__all(tm <= m_[qg] + 8.f)){       // defer-max (T13), exp2 domain
        const float mn = fmaxf(m_[qg], tm);
        const float sc = ex2(m_[qg] - mn);
        l_[qg] *= sc;
        #pragma unroll
        for (int jd=0;jd<4;jd++) xa[qg][jd] *= sc;
        m_[qg] = mn;
      }
      float rs = 0.f;
      #pragma unroll
      for (int t=0;t<4;t++){
        #pragma unroll
        for (int r=0;r<4;r++){
          const float pv = ex2(v[t*4+r] - m_[qg]);
          rs += pv;
          pq[qg][t][r] = (bf16)pv;
        }
      }
      rs += __shfl_xor(rs, 16, 64);
      rs += __shfl_xor(rs, 32, 64);
      l_[qg] += rs;
    }
    __builtin_amdgcn_s_setprio(1);
    #pragma unroll
    for (int t=0;t<4;t++){
      #pragma unroll
      for (int jd=0;jd<4;jd++){
        xa[0][jd] = mfma16bf(vv[t][jd], pq[0][t], xa[0][jd]);
        xa[1][jd] = mfma16bf(vv[t][jd], pq[1][t], xa[1][jd]);
      }
    }
    __builtin_amdgcn_s_setprio(0);
  };

  loadK(0, kA);
  for (int kv0=0; kv0<2048; kv0+=128){
    loadK(kv0+64, kB);                         // prefetch tile t+1
    compute(kv0, kA);
    if (kv0+128 < 2048) loadK(kv0+128, kA);    // prefetch tile t+2
    compute(kv0+64, kB);
  }

  // write O: lane holds q=l16 (per group), d = jd*16 + 4*g16 + r
  #pragma unroll
  for (int qg=0;qg<2;qg++){
    const float rl = 1.f / l_[qg];
    const size_t row = (size_t)(b*2048 + q0 + qg*16 + l16);
    #pragma unroll
    for (int jd=0;jd<4;jd++){
      bf16x4 ov = { f2b(xa[qg][jd][0]*rl), f2b(xa[qg][jd][1]*rl),
                    f2b(xa[qg][jd][2]*rl), f2b(xa[qg][jd][3]*rl) };
      *(bf16x4*)(O + row*1024 + h*64 + jd*16 + 4*g16) = ov;
    }
  }
}

// ---------------- residual + layernorm (row = 1024) ----------------
__global__ __launch_bounds__(256) void addln_kernel(
    const float* __restrict__ X, const float* __restrict__ R,
    const float* __restrict__ g, const float* __restrict__ be,
    float* __restrict__ of, bf16* __restrict__ ob)
{
  const int row = blockIdx.x, tid = threadIdx.x;
  const float4 vx = ((const float4*)(X + (size_t)row*1024))[tid];
  const float4 vr = ((const float4*)(R + (size_t)row*1024))[tid];
  const float a0 = vx.x+vr.x, a1 = vx.y+vr.y, a2 = vx.z+vr.z, a3 = vx.w+vr.w;
  float s = a0+a1+a2+a3;
  float q = a0*a0 + a1*a1 + a2*a2 + a3*a3;
  #pragma unroll
  for (int off=1; off<64; off<<=1){
    s += __shfl_xor(s, off, 64);
    q += __shfl_xor(q, off, 64);
  }
  __shared__ float sb[8];
  if ((tid&63)==0){ sb[tid>>6] = s; sb[4+(tid>>6)] = q; }
  __syncthreads();
  s = sb[0]+sb[1]+sb[2]+sb[3];
  q = sb[4]+sb[5]+sb[6]+sb[7];
  const float mu = s*(1.f/1024.f);
  const float rs = rsqrtf(q*(1.f/1024.f) - mu*mu + 1e-5f);
  const float4 gg = ((const float4*)g)[tid];
  const float4 bb = ((const float4*)be)[tid];
  const float o0 = (a0-mu)*rs*gg.x + bb.x;
  const float o1 = (a1-mu)*rs*gg.y + bb.y;
  const float o2 = (a2-mu)*rs*gg.z + bb.z;
  const float o3 = (a3-mu)*rs*gg.w + bb.w;
  float4 o; o.x=o0; o.y=o1; o.z=o2; o.w=o3;
  ((float4*)(of + (size_t)row*1024))[tid] = o;
  if (ob){
    bf16x4 u = { f2b(o0), f2b(o1), f2b(o2), f2b(o3) };
    *(bf16x4*)(ob + (size_t)row*1024 + tid*4) = u;
  }
}

// ---------------- launch ----------------
extern "C" void kernel_launch(void* const* d_in, const int* in_sizes, int n_in,
                              void* d_out, int out_size, void* d_ws, size_t ws_size,
                              hipStream_t stream)
{
  const float* src  = (const float*)d_in[0];
  const int*   mask = (const int*)  d_in[1];
  const float* Wq = (const float*)d_in[2];  const float* bq = (const float*)d_in[3];
  const float* Wk = (const float*)d_in[4];  const float* bk = (const float*)d_in[5];
  const float* Wv = (const float*)d_in[6];  const float* bv = (const float*)d_in[7];
  const float* Wo = (const float*)d_in[8];  const float* bo = (const float*)d_in[9];
  const float* W1 = (const float*)d_in[10]; const float* b1 = (const float*)d_in[11];
  const float* W2 = (const float*)d_in[12]; const float* b2 = (const float*)d_in[13];
  const float* g1 = (const float*)d_in[14]; const float* be1 = (const float*)d_in[15];
  const float* g2 = (const float*)d_in[16]; const float* be2 = (const float*)d_in[17];

  char* ws = (char*)d_ws;
  const size_t MB = 1u<<20;
  bf16* srcb = (bf16*)(ws + 0*MB);     // 16 MB  [dead after QKV gemms]
  bf16* Wqt  = (bf16*)(ws + 16*MB);    // 2 MB
  bf16* Wkt  = (bf16*)(ws + 18*MB);
  bf16* Wvt  = (bf16*)(ws + 20*MB);
  bf16* Wot  = (bf16*)(ws + 22*MB);
  bf16* W1t  = (bf16*)(ws + 24*MB);    // 8 MB
  bf16* W2t  = (bf16*)(ws + 32*MB);    // 8 MB
  bf16* Qb   = (bf16*)(ws + 40*MB);    // 16 MB [dead after attn]
  bf16* Kb   = (bf16*)(ws + 56*MB);    // 16 MB [dead after attn]
  bf16* Vtb  = (bf16*)(ws + 72*MB);    // 16 MB [dead after attn]
  bf16* AO   = (bf16*)(ws + 88*MB);    // 16 MB [dead after O-proj]
  float* X1  = (float*)(ws + 40*MB);   // 32 MB over Qb+Kb
  float* S1F = (float*)(ws + 72*MB);   // 32 MB over Vtb+AO
  bf16*  S1B = (bf16*)(ws + 0*MB);     // 16 MB over srcb
  bf16*  H1  = (bf16*)(ws + 104*MB);   // 64 MB
  float* F2  = (float*)(ws + 40*MB);   // 32 MB over X1 (dead after LN1)

  const float QSC = 0.18033688011112042f;   // 0.125 * log2(e)

  // casts + weight transposes
  castb_kernel<<<8192, 256, 0, stream>>>(src, srcb, 8192*1024/4);
  transcast_kernel<<<dim3(32,32),  dim3(32,8), 0, stream>>>(Wq, Wqt, 1024, 1024);
  transcast_kernel<<<dim3(32,32),  dim3(32,8), 0, stream>>>(Wk, Wkt, 1024, 1024);
  transcast_kernel<<<dim3(32,32),  dim3(32,8), 0, stream>>>(Wv, Wvt, 1024, 1024);
  transcast_kernel<<<dim3(32,32),  dim3(32,8), 0, stream>>>(Wo, Wot, 1024, 1024);
  transcast_kernel<<<dim3(128,32), dim3(32,8), 0, stream>>>(W1, W1t, 1024, 4096);
  transcast_kernel<<<dim3(32,128), dim3(32,8), 0, stream>>>(W2, W2t, 4096, 1024);

  // QKV projections (Q pre-scaled into exp2 softmax domain)
  gemm_bt_kernel<1><<<dim3(8,64),  256, 0, stream>>>(srcb, Wqt, bq, Qb,  8192, 1024, 1024, QSC);
  gemm_bt_kernel<1><<<dim3(8,64),  256, 0, stream>>>(srcb, Wkt, bk, Kb,  8192, 1024, 1024, 1.f);
  gemm_bt_kernel<3><<<dim3(8,64),  256, 0, stream>>>(srcb, Wvt, bv, Vtb, 8192, 1024, 1024, 1.f);

  // attention (1024 linear blocks, XCD-aware (b,h) clustering)
  attn_kernel<<<1024, 256, 0, stream>>>(Qb, Kb, Vtb, mask, AO);

  // output projection + LN1
  gemm_bt_kernel<0><<<dim3(8,64),  256, 0, stream>>>(AO, Wot, bo, X1, 8192, 1024, 1024, 1.f);
  addln_kernel<<<8192, 256, 0, stream>>>(X1, src, g1, be1, S1F, S1B);

  // FFN (swish) + LN2 -> d_out
  gemm_bt_kernel<2><<<dim3(32,64), 256, 0, stream>>>(S1B, W1t, b1, H1, 8192, 4096, 1024, 1.f);
  gemm_bt_kernel<0><<<dim3(8,64),  256, 0, stream>>>(H1,  W2t, b2, F2, 8192, 1024, 4096, 1.f);
  addln_kernel<<<8192, 256, 0, stream>>>(F2, S1F, g2, be2, (float*)d_out, (bf16*)nullptr);
}